// Round 11
// baseline (668.923 us; speedup 1.0000x reference)
//
#include <hip/hip_runtime.h>

// Social-LSTM on MI355X. fp32 I/O. 38 launches.
// Per frame: k_pool (1000 blk x 1024 thr: phase1 ballot->LDS index compaction,
//            phase2 balanced ILP-2 gather of U rows) -> k_gl (j2-permuted
//            gates GEMM + in-register LSTM) -> k_U (U for t+1 + out-proj of t).
// U[p][g*64+e] = sum_k h[p][k]*W_soc[e][g*128+k]; te = relu(sum_nz U + b_soc).

#define TT    12
#define NN    1000
#define RNNW  128
#define OUTD  5
#define GROW  16000     // N*G floats per (t,n) grid row
#define UCW   1024
#define NCHK  63        // ceil(16000/256)

__device__ __forceinline__ float sigmf(float x) { return 1.f / (1.f + __expf(-x)); }

// ---- prep: WsT (k-major W_soc), WcT (k-major, j2=r*4+gate permuted),
// bsum[j2]=b_ih+b_hh, h/c init (R9 verified) -------------------------------
__global__ void k_prep(const float* __restrict__ h0, const float* __restrict__ c0,
                       const float* __restrict__ W_soc,
                       const float* __restrict__ W_ih, const float* __restrict__ W_hh,
                       const float* __restrict__ b_ih, const float* __restrict__ b_hh,
                       float* __restrict__ h, float* __restrict__ c,
                       float* __restrict__ WsT, float* __restrict__ WcT,
                       float* __restrict__ bsum) {
    int i = blockIdx.x * 256 + threadIdx.x;
    if (i < 131072) {                       // WsT[gk][e] = W_soc[e][gk]
        int e = i >> 11, gk = i & 2047;
        WsT[gk * 64 + e] = W_soc[i];
    } else if (i < 196608) {                // W_ih [512][128] -> WcT[k][j2]
        int i2 = i - 131072;
        int j = i2 >> 7, k = i2 & 127;
        int j2 = (j & 127) * 4 + (j >> 7);
        WcT[k * 512 + j2] = W_ih[i2];
    } else if (i < 262144) {                // W_hh -> WcT[128+k][j2]
        int i3 = i - 196608;
        int j = i3 >> 7, k = i3 & 127;
        int j2 = (j & 127) * 4 + (j >> 7);
        WcT[(128 + k) * 512 + j2] = W_hh[i3];
    } else if (i < 262656) {                // bsum[j2]
        int j = i - 262144;
        int j2 = (j & 127) * 4 + (j >> 7);
        bsum[j2] = b_ih[j] + b_hh[j];
    } else if (i < 262656 + NN * RNNW) {
        int i4 = i - 262656; h[i4] = h0[i4];
    } else if (i < 262656 + 2 * NN * RNNW) {
        int i5 = i - 262656 - NN * RNNW; c[i5] = c0[i5];
    }
}

// ---- k_U: U for frame t+1 (R3/R9 verified) + out-proj of frame t ---------
__global__ __launch_bounds__(256) void k_U(const float* __restrict__ h,
                                           const float* __restrict__ WsT,
                                           const float* __restrict__ W_out,
                                           const float* __restrict__ b_out,
                                           float* __restrict__ U,
                                           float* __restrict__ out, int t) {
    __shared__ float sAT[RNNW][64];   // h^T tile (stays valid after GEMM)
    __shared__ float sBT[RNNW][64];
    const int tid = threadIdx.x;
    const int p0 = blockIdx.x * 64;
    const int g  = blockIdx.y;
    {   // stage sAT: transpose h[p0+pp][k] -> sAT[k][pp]
        int pp = tid >> 2, kq = (tid & 3) * 4;
        int p = p0 + pp;
        #pragma unroll
        for (int pass = 0; pass < 8; ++pass) {
            int k0 = pass * 16 + kq;
            float4 v = {0.f, 0.f, 0.f, 0.f};
            if (p < NN) v = *(const float4*)(h + (size_t)p * RNNW + k0);
            sAT[k0 + 0][pp] = v.x; sAT[k0 + 1][pp] = v.y;
            sAT[k0 + 2][pp] = v.z; sAT[k0 + 3][pp] = v.w;
        }
    }
    {   // stage sBT (rows g*128..+127 of WsT)
        #pragma unroll
        for (int pass = 0; pass < 8; ++pass) {
            int f = pass * 256 + tid;
            int k = f >> 4, e4 = (f & 15) * 4;
            float4 v = *(const float4*)(WsT + (size_t)(g * 128 + k) * 64 + e4);
            *(float4*)(&sBT[k][e4]) = v;
        }
    }
    __syncthreads();
    const int tx = tid & 15, ty = tid >> 4;
    float acc[4][4];
    #pragma unroll
    for (int i = 0; i < 4; i++)
        #pragma unroll
        for (int j = 0; j < 4; j++) acc[i][j] = 0.f;
    #pragma unroll 4
    for (int k = 0; k < RNNW; ++k) {
        float4 a4 = *(const float4*)(&sAT[k][ty * 4]);
        float4 b4 = *(const float4*)(&sBT[k][tx * 4]);
        const float av[4] = {a4.x, a4.y, a4.z, a4.w};
        const float bv[4] = {b4.x, b4.y, b4.z, b4.w};
        #pragma unroll
        for (int i = 0; i < 4; i++)
            #pragma unroll
            for (int j = 0; j < 4; j++) acc[i][j] += av[i] * bv[j];
    }
    #pragma unroll
    for (int i = 0; i < 4; i++) {
        int p = p0 + ty * 4 + i;
        if (p < NN) {
            float4 v = {acc[i][0], acc[i][1], acc[i][2], acc[i][3]};
            *(float4*)(U + (size_t)p * UCW + g * 64 + tx * 4) = v;
        }
    }
    // ---- out-proj of frame t from sAT (g==0 blocks) ----------------------
    if (t >= 0 && g == 0) {
        for (int task = tid; task < 64 * OUTD; task += 256) {
            int pp = task / OUTD, d = task - pp * OUTD;
            int p = p0 + pp;
            if (p < NN) {
                float s = b_out[d];
                const float* wr = W_out + d * RNNW;
                for (int k = 0; k < RNNW; ++k) s += sAT[k][pp] * wr[k];
                out[((size_t)t * NN + p) * OUTD + d] = s;
            }
        }
    }
}

// ---- pool: 1000 blocks x 1024 thr (16 waves) -----------------------------
// Phase 1: waves scan chunks c = it*16+wv, ballot-compact nz indices to LDS.
// Phase 2: balanced stride-16 gather of U rows with 2-way ILP.
__global__ __launch_bounds__(1024) void k_pool(const unsigned int* __restrict__ grd,
                                               const float* __restrict__ x_in,
                                               const float* __restrict__ U,
                                               const float* __restrict__ W_in,
                                               const float* __restrict__ b_in,
                                               const float* __restrict__ b_soc,
                                               float* __restrict__ A, int t) {
    __shared__ unsigned short sIdx[16 * 1024];   // 32 KB: per-wave segments
    __shared__ int sCnt[16];
    __shared__ float sAcc[16][64];
    const int n = blockIdx.x;
    const int tid = threadIdx.x;
    const int lane = tid & 63, wv = tid >> 6;    // 16 waves
    const unsigned int* gp = grd + ((size_t)t * NN + n) * (size_t)GROW;
    const unsigned long long lmask = (1ull << lane) - 1ull;

    // ---- phase 1: decode grid row into compacted index lists -------------
    {
        int wcnt = 0;
        unsigned short* seg = sIdx + wv * 1024;
        #pragma unroll
        for (int it = 0; it < 4; ++it) {
            int c = it * 16 + wv;
            if (c >= NCHK) break;
            int f0 = c * 256 + lane * 4;
            uint4 v = {0u, 0u, 0u, 0u};
            if (f0 < GROW) v = *(const uint4*)(gp + f0);
            unsigned int va[4] = {v.x, v.y, v.z, v.w};
            #pragma unroll
            for (int sub = 0; sub < 4; ++sub) {
                bool nz = (va[sub] != 0u);
                unsigned long long m = __ballot(nz);
                if (nz) {
                    int pos = wcnt + __popcll(m & lmask);
                    seg[pos] = (unsigned short)(f0 + sub);
                }
                wcnt += __popcll(m);
            }
        }
        if (lane == 0) sCnt[wv] = wcnt;
    }
    __syncthreads();
    // ---- phase 2: balanced gather (each wave strides all segments) -------
    {
        float a0 = 0.f, a1 = 0.f;
        for (int s = 0; s < 16; ++s) {
            const int cnt = sCnt[s];
            const unsigned short* seg = sIdx + s * 1024;
            int i = wv;
            for (; i + 16 < cnt; i += 32) {
                int f0 = seg[i], f1 = seg[i + 16];
                a0 += U[(size_t)(f0 >> 4) * UCW + (f0 & 15) * 64 + lane];
                a1 += U[(size_t)(f1 >> 4) * UCW + (f1 & 15) * 64 + lane];
            }
            if (i < cnt) {
                int f = seg[i];
                a0 += U[(size_t)(f >> 4) * UCW + (f & 15) * 64 + lane];
            }
        }
        sAcc[wv][lane] = a0 + a1;
    }
    __syncthreads();
    if (tid < 64) {
        float s = 0.f;
        #pragma unroll
        for (int w = 0; w < 16; w++) s += sAcc[w][tid];
        float te = fmaxf(s + b_soc[tid], 0.f);
        float x0 = x_in[((size_t)t * NN + n) * 2 + 0];
        float x1 = x_in[((size_t)t * NN + n) * 2 + 1];
        float ie = fmaxf(W_in[tid * 2 + 0] * x0 + W_in[tid * 2 + 1] * x1 + b_in[tid], 0.f);
        A[(size_t)n * RNNW + tid]      = ie;
        A[(size_t)n * RNNW + 64 + tid] = te;
    }
}

// ---- k_gl: gates GEMM (j2-permuted) + in-register LSTM (R9 verified) -----
__global__ __launch_bounds__(256) void k_gl(const float* __restrict__ A,
                                            const float* __restrict__ hin,
                                            float* __restrict__ hout,
                                            float* __restrict__ c,
                                            const float* __restrict__ WcT,
                                            const float* __restrict__ bsum,
                                            float* __restrict__ out, int t) {
    __shared__ float sAT[128][32];
    __shared__ float sBT[128][64];
    const int tid = threadIdx.x;
    const int n0 = blockIdx.x * 32;
    const int j0 = blockIdx.y * 64;
    const int tx = tid & 15, ty = tid >> 4;
    float acc[2][4];
    #pragma unroll
    for (int i = 0; i < 2; i++)
        #pragma unroll
        for (int j = 0; j < 4; j++) acc[i][j] = 0.f;
    for (int kc = 0; kc < 2; ++kc) {
        __syncthreads();
        {   // stage sAT: kc=0 from A=[ie|te], kc=1 from h(t-1)
            int nn = tid >> 3, kq = (tid & 7) * 4;
            int n = n0 + nn;
            const float* src = kc ? (hin + (size_t)n * RNNW) : (A + (size_t)n * RNNW);
            #pragma unroll
            for (int pass = 0; pass < 4; ++pass) {
                int k0 = pass * 32 + kq;
                float4 v = {0.f, 0.f, 0.f, 0.f};
                if (n < NN) v = *(const float4*)(src + k0);
                sAT[k0 + 0][nn] = v.x; sAT[k0 + 1][nn] = v.y;
                sAT[k0 + 2][nn] = v.z; sAT[k0 + 3][nn] = v.w;
            }
        }
        {   // stage sBT: WcT rows kc*128..+127, cols j0..j0+63
            #pragma unroll
            for (int pass = 0; pass < 8; ++pass) {
                int f = pass * 256 + tid;
                int k = f >> 4, e4 = (f & 15) * 4;
                float4 v = *(const float4*)(WcT + (size_t)(kc * 128 + k) * 512 + j0 + e4);
                *(float4*)(&sBT[k][e4]) = v;
            }
        }
        __syncthreads();
        #pragma unroll 4
        for (int k = 0; k < 128; ++k) {
            float2 a2 = *(const float2*)(&sAT[k][ty * 2]);
            float4 b4 = *(const float4*)(&sBT[k][tx * 4]);
            const float av[2] = {a2.x, a2.y};
            const float bv[4] = {b4.x, b4.y, b4.z, b4.w};
            #pragma unroll
            for (int i = 0; i < 2; i++)
                #pragma unroll
                for (int j = 0; j < 4; j++) acc[i][j] += av[i] * bv[j];
        }
    }
    // ---- epilogue: acc[i] = {i,f,g,o} gates of (n, r) -> LSTM ------------
    float4 bs = *(const float4*)(bsum + j0 + tx * 4);
    const int r = (j0 >> 2) + tx;
    #pragma unroll
    for (int i = 0; i < 2; i++) {
        int n = n0 + ty * 2 + i;
        if (n < NN) {
            float gi = acc[i][0] + bs.x;
            float gf = acc[i][1] + bs.y;
            float gg = acc[i][2] + bs.z;
            float go = acc[i][3] + bs.w;
            float cn = sigmf(gf) * c[(size_t)n * RNNW + r] + sigmf(gi) * tanhf(gg);
            float hn = sigmf(go) * tanhf(cn);
            c[(size_t)n * RNNW + r] = cn;
            hout[(size_t)n * RNNW + r] = hn;
            if (t == TT - 1) {   // final h,c tail of d_out
                out[(size_t)TT * NN * OUTD + (size_t)n * RNNW + r] = hn;
                out[(size_t)TT * NN * OUTD + (size_t)NN * RNNW + (size_t)n * RNNW + r] = cn;
            }
        }
    }
}

// ---- tail: out-proj of frame 11 ------------------------------------------
__global__ __launch_bounds__(256) void k_tail(const float* __restrict__ h,
                                              const float* __restrict__ W_out,
                                              const float* __restrict__ b_out,
                                              float* __restrict__ out) {
    int task = blockIdx.x * 256 + threadIdx.x;       // 5000 tasks
    if (task < NN * OUTD) {
        int p = task / OUTD, d = task - p * OUTD;
        float s = b_out[d];
        const float* wr = W_out + d * RNNW;
        const float* hp = h + (size_t)p * RNNW;
        for (int k = 0; k < RNNW; ++k) s += hp[k] * wr[k];
        out[((size_t)(TT - 1) * NN + p) * OUTD + d] = s;
    }
}

extern "C" void kernel_launch(void* const* d_in, const int* in_sizes, int n_in,
                              void* d_out, int out_size, void* d_ws, size_t ws_size,
                              hipStream_t stream) {
    const float* x_in       = (const float*)d_in[0];
    const unsigned int* grd = (const unsigned int*)d_in[1];
    const float* h0         = (const float*)d_in[2];
    const float* c0         = (const float*)d_in[3];
    const float* W_in       = (const float*)d_in[4];
    const float* b_in       = (const float*)d_in[5];
    const float* W_soc      = (const float*)d_in[6];
    const float* b_soc      = (const float*)d_in[7];
    const float* W_ih       = (const float*)d_in[8];
    const float* W_hh       = (const float*)d_in[9];
    const float* b_ih       = (const float*)d_in[10];
    const float* b_hh       = (const float*)d_in[11];
    const float* W_out      = (const float*)d_in[12];
    const float* b_out      = (const float*)d_in[13];
    float* out = (float*)d_out;

    float* hb0  = (float*)d_ws;                  // 128000
    float* hb1  = hb0 + NN * RNNW;               // 128000
    float* c    = hb1 + NN * RNNW;               // 128000
    float* U    = c + NN * RNNW;                 // 1,024,000
    float* A    = U + (size_t)NN * UCW;          // 128,000
    float* WsT  = A + (size_t)NN * RNNW;         // 131,072
    float* WcT  = WsT + 131072;                  // 131,072
    float* bsum = WcT + 131072;                  // 512

    hipLaunchKernelGGL(k_prep, dim3(2026), dim3(256), 0, stream,
                       h0, c0, W_soc, W_ih, W_hh, b_ih, b_hh, hb0, c, WsT, WcT, bsum);
    hipLaunchKernelGGL(k_U, dim3(16, 16), dim3(256), 0, stream,
                       hb0, WsT, W_out, b_out, U, out, -1);
    for (int t = 0; t < TT; ++t) {
        float* hin  = (t & 1) ? hb1 : hb0;
        float* hout = (t & 1) ? hb0 : hb1;
        hipLaunchKernelGGL(k_pool, dim3(NN), dim3(1024), 0, stream,
                           grd, x_in, U, W_in, b_in, b_soc, A, t);
        hipLaunchKernelGGL(k_gl, dim3(32, 8), dim3(256), 0, stream,
                           A, hin, hout, c, WcT, bsum, out, t);
        if (t < TT - 1) {
            hipLaunchKernelGGL(k_U, dim3(16, 16), dim3(256), 0, stream,
                               hout, WsT, W_out, b_out, U, out, t);
        }
    }
    hipLaunchKernelGGL(k_tail, dim3(20), dim3(256), 0, stream,
                       hb0, W_out, b_out, out);
}